// Round 6
// baseline (308.331 us; speedup 1.0000x reference)
//
#include <hip/hip_runtime.h>

#define CIN_B 512
#define CIN_F0 40
#define CIN_D 32
#define CIN_S 200

typedef short bf16x8 __attribute__((ext_vector_type(8)));
typedef float floatx16 __attribute__((ext_vector_type(16)));

__device__ __forceinline__ float bits2f(unsigned int u) {
    union { unsigned int i; float f; } c; c.i = u; return c.f;
}
__device__ __forceinline__ unsigned short f2b(float f) {
    union { float f; unsigned int i; } c; c.f = f;
    unsigned int i = c.i;
    return (unsigned short)((i + 0x7fffu + ((i >> 16) & 1u)) >> 16);  // RNE
}
__device__ __forceinline__ float b2f(unsigned short u) {
    return bits2f(((unsigned int)u) << 16);
}

// Wtk[kc][nn 0..255][kw 0..15] = bf16(W[(i*FI + kk*16+kw)*200 + nn]); kc = i*KCPI+kk.
// Zero-pad nn>=200 and j>=FI. One block per kc; coalesced W reads (nn = lane).
template <int FI, int KCPI>
__global__ __launch_bounds__(256) void prep_w(const float* __restrict__ W,
                                              unsigned short* __restrict__ Wtk) {
    const int kc = blockIdx.x;
    const int nn = threadIdx.x;
    const int i = kc / KCPI;
    const int kk = kc - i * KCPI;
    unsigned short v[16];
#pragma unroll
    for (int kw = 0; kw < 16; ++kw) {
        int j = kk * 16 + kw;
        float f = 0.f;
        if (j < FI && nn < CIN_S) f = W[(size_t)(i * FI + j) * CIN_S + nn];
        v[kw] = f2b(f);
    }
    uint4* dst = (uint4*)(Wtk + ((size_t)kc * 256 + nn) * 16);
    dst[0] = ((const uint4*)v)[0];
    dst[1] = ((const uint4*)v)[1];
}

// fused variant for the two big weight matrices (same shape)
__global__ __launch_bounds__(256) void prep_w2(const float* __restrict__ Wa,
                                               unsigned short* __restrict__ Wta,
                                               const float* __restrict__ Wb,
                                               unsigned short* __restrict__ Wtb) {
    const int half = blockIdx.x >= 560;
    const int kc = half ? blockIdx.x - 560 : blockIdx.x;
    const float* W = half ? Wb : Wa;
    unsigned short* Wtk = half ? Wtb : Wta;
    const int nn = threadIdx.x;
    const int i = kc / 14;
    const int kk = kc - i * 14;
    unsigned short v[16];
#pragma unroll
    for (int kw = 0; kw < 16; ++kw) {
        int j = kk * 16 + kw;
        float f = 0.f;
        if (j < CIN_S && nn < CIN_S) f = W[(size_t)(i * CIN_S + j) * CIN_S + nn];
        v[kw] = f2b(f);
    }
    uint4* dst = (uint4*)(Wtk + ((size_t)kc * 256 + nn) * 16);
    dst[0] = ((const uint4*)v)[0];
    dst[1] = ((const uint4*)v)[1];
}

// X0h[b][d][i(pad 48)] = bf16(x0[b][i][d]);  Xs[b][i][d] = fp32 x0.
__global__ __launch_bounds__(256) void prep_x(const float* __restrict__ X,
                                              unsigned short* __restrict__ X0h,
                                              float* __restrict__ Xs) {
    int e = blockIdx.x * 256 + threadIdx.x;   // 512*40*32
    int d = e & 31;
    int rest = e >> 5;
    int i = rest % CIN_F0;
    int b = rest / CIN_F0;
    float v = X[e];
    Xs[e] = v;
    X0h[((size_t)b * CIN_D + d) * 48 + i] = f2b(v);
    if (e < CIN_B * CIN_D * 8) {     // zero pads i=40..47
        int q = e & 7, dd = (e >> 3) & 31, bb = e >> 8;
        X0h[((size_t)bb * CIN_D + dd) * 48 + 40 + q] = 0;
    }
}

// Layer: Hout[b][d][n] = sum_i x0[b][i][d] * (sum_j Wt[n,(i,j)] * h[b][j][d])
// Grid: 256 blocks (2 b each) x 7 waves; wave = one 32-row n-tile x 2 b, full K.
// Each A-fragment load feeds 2 MFMA chains (b0,b1) -> halves L2 A-traffic and
// doubles chain ILP. B-frags (h only, i-invariant) live in VGPRs; no LDS.
// mfma_f32_32x32x16_bf16: A[m=lane&31][k=(lane>>5)*8+e] (m = n-row);
// B[k][col=lane&31] (col = d); C/D col=lane&31, row=(reg&3)+8*(reg>>2)+4*(lane>>5).
template <int KCPI, int JROW>
__global__ __launch_bounds__(448, 2)
void cin_layer(const unsigned short* __restrict__ Hin,   // [b][32][JROW] bf16
               const float* __restrict__ Xs,             // [b][40][32] fp32
               const unsigned short* __restrict__ Wtk,   // [kc][256][16] bf16
               unsigned short* __restrict__ Hout) {      // [b][32][224] bf16
    const int b0 = blockIdx.x * 2;
    const int wave = threadIdx.x >> 6;       // 0..6 == n-tile
    const int lane = threadIdx.x & 63;
    const int l32 = lane & 31, hl = lane >> 5;
    const int tile = wave;

    // B-frags: Bf{0,1}[kk] lane holds h[b0+{0,1}][d=l32][j = kk*16 + hl*8 + e]
    bf16x8 Bf0[KCPI], Bf1[KCPI];
    {
        const unsigned short* h0 = Hin + ((size_t)b0 * CIN_D + l32) * JROW + hl * 8;
        const unsigned short* h1 = h0 + (size_t)CIN_D * JROW;
#pragma unroll
        for (int kk = 0; kk < KCPI; ++kk) {
            Bf0[kk] = *(const bf16x8*)(h0 + kk * 16);
            Bf1[kk] = *(const bf16x8*)(h1 + kk * 16);
        }
    }

    const unsigned short* Abase = Wtk + ((size_t)(tile * 32 + l32) * 16 + hl * 8);
    const float* xs0 = Xs + (size_t)b0 * (CIN_F0 * CIN_D) + l32;

    floatx16 acc0, acc1, z16;
#pragma unroll
    for (int r = 0; r < 16; ++r) { acc0[r] = 0.f; acc1[r] = 0.f; z16[r] = 0.f; }

#pragma unroll 1
    for (int i = 0; i < CIN_F0; ++i) {
        const float x0 = xs0[(size_t)i * CIN_D];
        const float x1 = xs0[(size_t)i * CIN_D + CIN_F0 * CIN_D];
        floatx16 P0, P1;
#pragma unroll
        for (int kk = 0; kk < KCPI; ++kk) {
            const bf16x8 Af =
                *(const bf16x8*)(Abase + (size_t)(i * KCPI + kk) * 4096);
            P0 = __builtin_amdgcn_mfma_f32_32x32x16_bf16(Af, Bf0[kk],
                                                         (kk == 0) ? z16 : P0, 0, 0, 0);
            P1 = __builtin_amdgcn_mfma_f32_32x32x16_bf16(Af, Bf1[kk],
                                                         (kk == 0) ? z16 : P1, 0, 0, 0);
        }
#pragma unroll
        for (int r = 0; r < 16; ++r) {
            acc0[r] += x0 * P0[r];
            acc1[r] += x1 * P1[r];
        }
    }

    // epilogue: C[n][d] -> Hout[b][d][n]; rows = (reg&3)+8*qd+4*hl, col = l32
#pragma unroll
    for (int bb = 0; bb < 2; ++bb) {
        const floatx16& a = bb ? acc1 : acc0;
        unsigned short* dst = Hout + ((size_t)(b0 + bb) * CIN_D + l32) * 224 + tile * 32;
#pragma unroll
        for (int qd = 0; qd < 4; ++qd) {
            ushort4 pk;
            pk.x = f2b(a[4 * qd + 0]);
            pk.y = f2b(a[4 * qd + 1]);
            pk.z = f2b(a[4 * qd + 2]);
            pk.w = f2b(a[4 * qd + 3]);
            *(ushort4*)&dst[8 * qd + 4 * hl] = pk;
        }
    }
}

// out[b, l*200+n] = sum_d H_l[b][d][n]
__global__ __launch_bounds__(256) void cin_reduce(const unsigned short* __restrict__ H1,
                                                  const unsigned short* __restrict__ H2,
                                                  const unsigned short* __restrict__ H3,
                                                  float* __restrict__ out) {
    __shared__ __align__(16) unsigned short L[CIN_D][224];
    const int bid = blockIdx.x;            // 0..1535
    const int b = bid / 3, l = bid % 3;
    const unsigned short* H = (l == 0 ? H1 : (l == 1 ? H2 : H3)) + (size_t)b * CIN_D * 224;
    const uint4* src = (const uint4*)H;
    for (int g = threadIdx.x; g < CIN_D * 224 / 8; g += 256) {
        int r = g / 28, c = g - r * 28;
        *(uint4*)&L[r][c * 8] = src[g];
    }
    __syncthreads();
    int n = threadIdx.x;
    if (n < CIN_S) {
        float s = 0.f;
#pragma unroll
        for (int dd = 0; dd < CIN_D; ++dd) s += b2f(L[dd][n]);
        out[(size_t)b * (3 * CIN_S) + l * CIN_S + n] = s;
    }
}

extern "C" void kernel_launch(void* const* d_in, const int* in_sizes, int n_in,
                              void* d_out, int out_size, void* d_ws, size_t ws_size,
                              hipStream_t stream) {
    const float* X  = (const float*)d_in[0];
    const float* W0 = (const float*)d_in[1];
    const float* W1 = (const float*)d_in[2];
    const float* W2 = (const float*)d_in[3];
    float* out = (float*)d_out;

    unsigned short* Wtk1 = (unsigned short*)d_ws;            // 120*256*16
    unsigned short* Wtk2 = Wtk1 + (size_t)120 * 4096;        // 560*256*16
    unsigned short* Wtk3 = Wtk2 + (size_t)560 * 4096;
    unsigned short* X0h  = Wtk3 + (size_t)560 * 4096;        // 512*32*48
    unsigned short* H1   = X0h + (size_t)CIN_B * CIN_D * 48; // 512*32*224 each
    unsigned short* H2   = H1 + (size_t)CIN_B * CIN_D * 224;
    unsigned short* H3   = H2 + (size_t)CIN_B * CIN_D * 224;
    float* Xs = (float*)(H3 + (size_t)CIN_B * CIN_D * 224);  // 512*40*32 fp32
    // total ws ~36.4 MB

    prep_w<CIN_F0, 3><<<120, 256, 0, stream>>>(W0, Wtk1);
    prep_w2<<<1120, 256, 0, stream>>>(W1, Wtk2, W2, Wtk3);
    prep_x<<<(CIN_B * CIN_F0 * CIN_D) / 256, 256, 0, stream>>>(X, X0h, Xs);

    cin_layer<3, 48><<<CIN_B / 2, 448, 0, stream>>>(X0h, Xs, Wtk1, H1);
    cin_layer<14, 224><<<CIN_B / 2, 448, 0, stream>>>(H1, Xs, Wtk2, H2);
    cin_layer<14, 224><<<CIN_B / 2, 448, 0, stream>>>(H2, Xs, Wtk3, H3);

    cin_reduce<<<CIN_B * 3, 256, 0, stream>>>(H1, H2, H3, out);
}